// Round 21
// baseline (296.845 us; speedup 1.0000x reference)
//
#include <hip/hip_runtime.h>

#define T_TOK 4096
#define DDIM 1024
#define FDIM 4096
#define NE 8
#define NPAIR 8192
#define MAXT128 72
#define MAXT256 48
#define EOSLAB ((size_t)(NPAIR + 256) * DDIM)

typedef short bf16x8 __attribute__((ext_vector_type(8)));
typedef float f32x4 __attribute__((ext_vector_type(4)));

__device__ inline unsigned short f2bf(float f) {
  union { float f; unsigned u; } a; a.f = f;
  unsigned r = a.u + 0x7fffu + ((a.u >> 16) & 1u);
  return (unsigned short)(r >> 16);
}

__device__ inline float bf2f(ushort u) {
  union { unsigned u; float f; } a; a.u = ((unsigned)u) << 16;
  return a.f;
}

__device__ __forceinline__ void gload16(const void* g, void* l) {
  __builtin_amdgcn_global_load_lds(
      (const __attribute__((address_space(1))) unsigned int*)g,
      (__attribute__((address_space(3))) unsigned int*)l, 16, 0, 0);
}

// ---------------- fused: router (blocks 0..1023) + W1 transpose (blocks 1024..9215) ----------------
__global__ __launch_bounds__(256) void router_w1t_kernel(
    const float* __restrict__ x, const float* __restrict__ noise,
    const float* __restrict__ Wr, const float* __restrict__ br,
    const float* __restrict__ Wn, const float* __restrict__ bn,
    int* __restrict__ tok_top, float* __restrict__ tok_gate,
    ushort* __restrict__ xb,
    const float* __restrict__ W1, ushort* __restrict__ WT1)
{
  if (blockIdx.x >= 1024) {
    __shared__ float tile[64][65];
    int idx = blockIdx.x - 1024;
    int z = idx >> 10;
    int rem = idx & 1023;
    int bx = rem & 63, by = rem >> 6;
    const float* src = W1 + (size_t)z * DDIM * FDIM;
    ushort* dst = WT1 + (size_t)z * FDIM * DDIM;
    int c0 = bx * 64, r0 = by * 64;
    int tid = threadIdx.x;
    int tr = tid >> 4;
    int tc4 = (tid & 15) * 4;
#pragma unroll
    for (int i = 0; i < 64; i += 16) {
      float4 v = *(const float4*)(src + (size_t)(r0 + tr + i) * FDIM + c0 + tc4);
      tile[tr + i][tc4] = v.x; tile[tr + i][tc4 + 1] = v.y;
      tile[tr + i][tc4 + 2] = v.z; tile[tr + i][tc4 + 3] = v.w;
    }
    __syncthreads();
    int rr = (tid & 7) * 8;
    int cbase = tid >> 3;
#pragma unroll
    for (int cc = 0; cc < 64; cc += 32) {
      int c = cbase + cc;
      ushort tmp[8];
#pragma unroll
      for (int j = 0; j < 8; ++j) tmp[j] = f2bf(tile[rr + j][c]);
      *(uint4*)(dst + (size_t)(c0 + c) * DDIM + r0 + rr) = *(uint4*)tmp;
    }
    return;
  }
  int t = blockIdx.x * 4 + (threadIdx.x >> 6);
  int lane = threadIdx.x & 63;
  const float* xr = x + (size_t)t * DDIM;
  ushort* xo = xb + (size_t)t * DDIM;
  float accR[NE] = {}, accN[NE] = {};
  for (int d = lane; d < DDIM; d += 64) {
    float xv = xr[d];
    xo[d] = f2bf(xv);
    const float* wr = Wr + (size_t)d * NE;
    const float* wn = Wn + (size_t)d * NE;
#pragma unroll
    for (int e = 0; e < NE; ++e) {
      accR[e] = fmaf(xv, wr[e], accR[e]);
      accN[e] = fmaf(xv, wn[e], accN[e]);
    }
  }
#pragma unroll
  for (int off = 32; off > 0; off >>= 1) {
#pragma unroll
    for (int e = 0; e < NE; ++e) {
      accR[e] += __shfl_xor(accR[e], off);
      accN[e] += __shfl_xor(accN[e], off);
    }
  }
  if (lane == 0) {
    float noisy[NE];
#pragma unroll
    for (int e = 0; e < NE; ++e) {
      float lg = accR[e] + br[e];
      float nl = accN[e] + bn[e];
      float sp = fmaxf(nl, 0.f) + log1pf(expf(-fabsf(nl)));
      noisy[e] = lg + noise[(size_t)t * NE + e] * sp;
    }
    int e0 = 0;
#pragma unroll
    for (int e = 1; e < NE; ++e) if (noisy[e] > noisy[e0]) e0 = e;
    int e1 = (e0 == 0) ? 1 : 0;
#pragma unroll
    for (int e = 0; e < NE; ++e)
      if (e != e0 && e != e1 && noisy[e] > noisy[e1]) e1 = e;
    float v0 = noisy[e0], v1 = noisy[e1];
    float ex = __expf(v1 - v0);
    float inv = 1.f / (1.f + ex);
    tok_top[t * 2] = e0; tok_top[t * 2 + 1] = e1;
    tok_gate[t * 2] = inv; tok_gate[t * 2 + 1] = ex * inv;
  }
}

// ---------------- deterministic count + PARALLEL scan + dual tile lists + scatter ----------------
__global__ __launch_bounds__(256) void scan_scatter_kernel(
    const int* __restrict__ tok_top, int* __restrict__ off,
    int* __restrict__ tiles128, int* __restrict__ tiles256,
    int* __restrict__ pair_tok, int* __restrict__ tok_ppos)
{
  __shared__ int smat[NE][256];
  __shared__ int tot[NE];
  __shared__ int loff[NE];
  int tid = threadIdx.x;
  int c[NE] = {};
  for (int i = 0; i < 16; ++i) {
    int t = tid * 16 + i;
    int e0 = tok_top[2 * t], e1 = tok_top[2 * t + 1];
#pragma unroll
    for (int e = 0; e < NE; ++e) c[e] += (e0 == e) + (e1 == e);
  }
#pragma unroll
  for (int e = 0; e < NE; ++e) smat[e][tid] = c[e];
  __syncthreads();
  {
    int ge = tid >> 5;
    int gl = tid & 31;
    int vals[8], s = 0;
#pragma unroll
    for (int j = 0; j < 8; ++j) { vals[j] = smat[ge][gl * 8 + j]; s += vals[j]; }
    int incl = s;
#pragma unroll
    for (int d = 1; d < 32; d <<= 1) {
      int o = __shfl_up(incl, d);
      if (gl >= d) incl += o;
    }
    int run = incl - s;
#pragma unroll
    for (int j = 0; j < 8; ++j) { smat[ge][gl * 8 + j] = run; run += vals[j]; }
    if (gl == 31) tot[ge] = incl;
  }
  __syncthreads();
  if (tid == 0) {
    int s = 0, nt1 = 0, nt2 = 0;
    for (int e = 0; e < NE; ++e) {
      loff[e] = s; off[e] = s;
      int t1 = (tot[e] + 127) >> 7;
      for (int m = 0; m < t1; ++m) tiles128[1 + nt1++] = (e << 8) | m;
      int t2 = (tot[e] + 255) >> 8;
      for (int m = 0; m < t2; ++m) tiles256[1 + nt2++] = (e << 8) | m;
      s += tot[e];
    }
    off[NE] = s;
    tiles128[0] = nt1;
    tiles256[0] = nt2;
  }
  __syncthreads();
  for (int i = 0; i < 16; ++i) {
    int t = tid * 16 + i;
#pragma unroll
    for (int k = 0; k < 2; ++k) {
      int e = tok_top[2 * t + k];
      int pos = loff[e] + smat[e][tid];
      smat[e][tid] = smat[e][tid] + 1;
      pair_tok[pos] = t;
      tok_ppos[2 * t + k] = pos;
    }
  }
}

// ---------------- 256x256 8-phase counted-vmcnt grouped GEMM1, 8 waves (2Mx4N) ----------------
// Surplus blocks: transpose W2 -> WT2 (two 64x64 tiles per iter).
template<int KD, int ND, int INDIR>
__global__ __launch_bounds__(512) void gemm8p_kernel(
    const ushort* __restrict__ A, const ushort* __restrict__ BT,
    const int* __restrict__ off, const int* __restrict__ tiles,
    const int* __restrict__ pair_tok, const float* __restrict__ bias,
    ushort* __restrict__ Hout,
    const float* __restrict__ W2src, ushort* __restrict__ WT2dst)
{
  constexpr int GX = ND / 256;
  constexpr int NKT = KD / 64;
  constexpr int NIT = NKT / 2;
  __shared__ __align__(16) char lds[2 * 65536];

  int total = tiles[0] * GX;
  int orig = blockIdx.x + GX * (int)blockIdx.y;
  if (orig >= total) {
    int S = GX * (int)gridDim.y - total;
    int half = threadIdx.x >> 8;
    int tid2 = threadIdx.x & 255;
    float (*tt)[65] = (float(*)[65])(lds + half * 16704);
    int tr = tid2 >> 4, tc4 = (tid2 & 15) * 4;
    int rr = (tid2 & 7) * 8, cbase = tid2 >> 3;
    for (int j = orig - total; j < 4096; j += S) {
      int idx = 2 * j + half;
      int e2 = idx >> 10;
      int rem = idx & 1023;
      int ft = rem >> 4, dt = rem & 15;
      const float* src = W2src + (size_t)e2 * FDIM * DDIM;
      ushort* dst = WT2dst + (size_t)e2 * DDIM * FDIM;
      int r0 = ft * 64, c0 = dt * 64;
#pragma unroll
      for (int i = 0; i < 64; i += 16) {
        float4 v = *(const float4*)(src + (size_t)(r0 + tr + i) * DDIM + c0 + tc4);
        tt[tr + i][tc4] = v.x; tt[tr + i][tc4 + 1] = v.y;
        tt[tr + i][tc4 + 2] = v.z; tt[tr + i][tc4 + 3] = v.w;
      }
      __syncthreads();
#pragma unroll
      for (int cc = 0; cc < 64; cc += 32) {
        int c = cbase + cc;
        ushort tmp[8];
#pragma unroll
        for (int jj = 0; jj < 8; ++jj) tmp[jj] = f2bf(tt[rr + jj][c]);
        *(uint4*)(dst + (size_t)(c0 + c) * FDIM + r0 + rr) = *(uint4*)tmp;
      }
      __syncthreads();
    }
    return;
  }
  int q = total >> 3, r = total & 7, xcd = orig & 7, idx = orig >> 3;
  int wg = (xcd < r ? xcd * (q + 1) : r * (q + 1) + (xcd - r) * q) + idx;
  int ti = wg / GX, bx = wg - ti * GX;

  int te = tiles[1 + ti];
  int e = te >> 8, mt = te & 255;
  int base = off[e];
  int cnt = off[e + 1] - base;
  int m0 = mt << 8, n0 = bx << 8;

  int tid = threadIdx.x, lane = tid & 63, wid = tid >> 6;
  int wr = wid >> 2, wc = wid & 3;
  int lr = lane & 15, hi = lane >> 4;
  int swl = (lane & 7) << 4;
  int wrOff = wr * 16384;
  int wcLow = wc & 1;
  int wcHiOff = (wc >> 1) * 16384;

  const char* aptr[2][2];
  const char* bptr[2][2];
  {
    const char* Ab = (const char*)A;
    const char* Bb = (const char*)(BT + ((size_t)e * ND + n0) * KD);
#pragma unroll
    for (int h = 0; h < 2; ++h)
#pragma unroll
      for (int c = 0; c < 2; ++c) {
        int ch = c * 512 + tid;
        int rl = ch >> 3;
        int sc = ((ch & 7) * 16) ^ ((rl & 7) << 4);
        int mr = m0 + h * 128 + rl; if (mr >= cnt) mr = cnt - 1;
        int ar = INDIR ? pair_tok[base + mr] : base + mr;
        aptr[h][c] = Ab + (size_t)ar * (KD * 2) + sc;
        bptr[h][c] = Bb + (size_t)(h * 128 + rl) * (KD * 2) + sc;
      }
  }

#define SH_A(T, H)                                                        \
  if ((T) < NKT) {                                                        \
    char* d_ = lds + ((T) & 1) * 65536 + (H) * 16384 + tid * 16;          \
    gload16(aptr[H][0] + (T) * 128, d_);                                  \
    gload16(aptr[H][1] + (T) * 128, d_ + 8192);                           \
  }
#define SH_B(T, H)                                                        \
  if ((T) < NKT) {                                                        \
    char* d_ = lds + ((T) & 1) * 65536 + 32768 + (H) * 16384 + tid * 16;  \
    gload16(bptr[H][0] + (T) * 128, d_);                                  \
    gload16(bptr[H][1] + (T) * 128, d_ + 8192);                           \
  }
#define LDA(MH, BUF)                                                      \
  { _Pragma("unroll") for (int mm = 0; mm < 4; ++mm) {                    \
      int rr_ = (MH) * 64 + mm * 16 + lr;                                 \
      _Pragma("unroll") for (int ks = 0; ks < 2; ++ks)                    \
        af[mm][ks] = *(const bf16x8*)((BUF) + wrOff + rr_ * 128 +         \
                                      ((ks * 64 + hi * 16) ^ swl)); } }
#define LDB(NH, BUF, BV)                                                  \
  { _Pragma("unroll") for (int nn = 0; nn < 2; ++nn) {                    \
      int rr_ = wcLow * 64 + (NH) * 32 + nn * 16 + lr;                    \
      _Pragma("unroll") for (int ks = 0; ks < 2; ++ks)                    \
        BV[nn][ks] = *(const bf16x8*)((BUF) + 32768 + wcHiOff + rr_ * 128 + \
                                      ((ks * 64 + hi * 16) ^ swl)); } }
#define MMA(MH, NH, BV)                                                   \
  { _Pragma("unroll") for (int ks = 0; ks < 2; ++ks)                      \
    _Pragma("unroll") for (int mm = 0; mm < 4; ++mm)                      \
    _Pragma("unroll") for (int nn = 0; nn < 2; ++nn)                      \
      acc[(MH) * 4 + mm][(NH) * 2 + nn] =                                 \
        __builtin_amdgcn_mfma_f32_16x16x32_bf16(                          \
          af[mm][ks], BV[nn][ks], acc[(MH) * 4 + mm][(NH) * 2 + nn], 0, 0, 0); }
#define PH_MID                                                            \
  __builtin_amdgcn_sched_barrier(0);                                      \
  __builtin_amdgcn_s_barrier();                                           \
  asm volatile("s_waitcnt lgkmcnt(0)" ::: "memory");                      \
  __builtin_amdgcn_sched_barrier(0);                                      \
  __builtin_amdgcn_s_setprio(1);
#define PH_END                                                            \
  __builtin_amdgcn_s_setprio(0);                                          \
  __builtin_amdgcn_sched_barrier(0);                                      \
  __builtin_amdgcn_s_barrier();

  f32x4 acc[8][4] = {};
  bf16x8 af[4][2], bv0[2][2], bv1[2][2];

  SH_A(0, 0); SH_A(0, 1); SH_B(0, 0); SH_B(0, 1); SH_B(1, 0); SH_B(1, 1);
  asm volatile("s_waitcnt vmcnt(4)" ::: "memory");
  __builtin_amdgcn_sched_barrier(0);
  __builtin_amdgcn_s_barrier();

  const char* buf0 = lds;
  const char* buf1 = lds + 65536;

  for (int it = 0; it < NIT; ++it) {
    int t0 = 2 * it, t1 = t0 + 1;
    LDA(0, buf0); LDB(0, buf0, bv0);
    SH_A(t1, 0);
    PH_MID; MMA(0, 0, bv0); PH_END;
    LDB(1, buf0, bv1);
    SH_A(t1, 1);
    PH_MID; MMA(0, 1, bv1); PH_END;
    LDA(1, buf0);
    SH_B(t0 + 2, 0);
    PH_MID; MMA(1, 1, bv1); PH_END;
    SH_A(t0 + 2, 0);
    PH_MID; MMA(1, 0, bv0);
    __builtin_amdgcn_s_setprio(0);
    if (t0 + 2 < NKT) asm volatile("s_waitcnt vmcnt(4)" ::: "memory");
    else              asm volatile("s_waitcnt vmcnt(0)" ::: "memory");
    __builtin_amdgcn_sched_barrier(0);
    __builtin_amdgcn_s_barrier();
    LDA(0, buf1); LDB(0, buf1, bv0);
    SH_A(t0 + 2, 1);
    PH_MID; MMA(0, 0, bv0); PH_END;
    LDB(1, buf1, bv1);
    SH_B(t0 + 2, 1);
    PH_MID; MMA(0, 1, bv1); PH_END;
    LDA(1, buf1);
    SH_B(t1 + 2, 0);
    PH_MID; MMA(1, 1, bv1); PH_END;
    SH_B(t1 + 2, 1);
    PH_MID; MMA(1, 0, bv0);
    __builtin_amdgcn_s_setprio(0);
    if (t1 + 2 < NKT) asm volatile("s_waitcnt vmcnt(4)" ::: "memory");
    else              asm volatile("s_waitcnt vmcnt(0)" ::: "memory");
    __builtin_amdgcn_sched_barrier(0);
    __builtin_amdgcn_s_barrier();
  }

  int rq = hi << 2;
#pragma unroll
  for (int m = 0; m < 8; ++m) {
#pragma unroll
    for (int qq = 0; qq < 4; ++qq) {
      int rr2 = m0 + wr * 128 + m * 16 + rq + qq;
      if (rr2 < cnt) {
#pragma unroll
        for (int n = 0; n < 4; ++n) {
          int col = n0 + wc * 64 + n * 16 + lr;
          float v = fmaxf(acc[m][n][qq] + bias[(size_t)e * ND + col], 0.f);
          Hout[(size_t)(base + rr2) * ND + col] = f2bf(v);
        }
      }
    }
  }
#undef SH_A
#undef SH_B
#undef LDA
#undef LDB
#undef MMA
#undef PH_MID
#undef PH_END
}

// ---------------- GEMM2: 128x128, 4 waves, BK=64, 32KB single-buffer (locked R11 body) ----------------
// splitK=2 via grid: kh=rem&1, K-half=2048; EO partial bf16; b2 added by kh==0 half only.
template<int KD, int ND>
__global__ __launch_bounds__(256) void gemm4_kernel(
    const ushort* __restrict__ A, const ushort* __restrict__ BT,
    const int* __restrict__ off, const int* __restrict__ tiles,
    const float* __restrict__ bias, ushort* __restrict__ EOout)
{
  constexpr int GX = ND / 128;
  constexpr int NKT = KD / 2 / 64;   // 32 per half
  __shared__ __align__(16) ushort As[128 * 64];
  __shared__ __align__(16) ushort Bs[128 * 64];

  int total = tiles[0] * GX * 2;
  int orig = blockIdx.x + (GX * 2) * (int)blockIdx.y;
  if (orig >= total) return;
  int q = total >> 3, r = total & 7, xcd = orig & 7, idx = orig >> 3;
  int wg = (xcd < r ? xcd * (q + 1) : r * (q + 1) + (xcd - r) * q) + idx;
  int ti = wg / (GX * 2);
  int rem = wg % (GX * 2);
  int bx = rem >> 1, kh = rem & 1;

  int te = tiles[1 + ti];
  int e = te >> 8, mt = te & 255;
  int base = off[e];
  int cnt = off[e + 1] - base;
  int m0 = mt << 7, n0 = bx << 7;
  int k0b = kh * (KD / 2) * 2;   // byte offset of K-half

  int tid = threadIdx.x, lane = tid & 63, wid = tid >> 6;
  int wr = wid >> 1, wc = wid & 1;

  int arow[4];
#pragma unroll
  for (int c = 0; c < 4; ++c) {
    int rl = (c * 256 + tid) >> 3;
    int mr = m0 + rl; if (mr >= cnt) mr = cnt - 1;
    arow[c] = base + mr;
  }
  const char* Ab = (const char*)A + k0b;
  const char* Bgb = (const char*)(BT + ((size_t)e * ND + n0) * KD) + k0b;

  f32x4 acc[4][4] = {};

  for (int t = 0; t < NKT; ++t) {
    __syncthreads();
    int kb = t * 128;
#pragma unroll
    for (int c = 0; c < 4; ++c) {
      int ch = c * 256 + tid;
      int row = ch >> 3, b = (ch & 7) * 16;
      gload16(Ab + (size_t)arow[c] * (KD * 2) + kb + (b ^ ((row & 7) << 4)),
              (char*)As + ch * 16);
    }
#pragma unroll
    for (int c = 0; c < 4; ++c) {
      int ch = c * 256 + tid;
      int row = ch >> 3, b = (ch & 7) * 16;
      gload16(Bgb + (size_t)row * (KD * 2) + kb + (b ^ ((row & 7) << 4)),
              (char*)Bs + ch * 16);
    }
    __syncthreads();

    bf16x8 af[4][2], bv[4][2];
#pragma unroll
    for (int m = 0; m < 4; ++m) {
      int row = wr * 64 + m * 16 + (lane & 15);
      int sw = (row & 7) << 4;
#pragma unroll
      for (int ks = 0; ks < 2; ++ks)
        af[m][ks] = *(const bf16x8*)((const char*)As + row * 128 +
                                     ((ks * 64 + (lane >> 4) * 16) ^ sw));
    }
#pragma unroll
    for (int n = 0; n < 4; ++n) {
      int row = wc * 64 + n * 16 + (lane & 15);
      int sw = (row & 7) << 4;
#pragma unroll
      for (int ks = 0; ks < 2; ++ks)
        bv[n][ks] = *(const bf16x8*)((const char*)Bs + row * 128 +
                                     ((ks * 64 + (lane >> 4) * 16) ^ sw));
    }
#pragma unroll
    for (int ks = 0; ks < 2; ++ks)
#pragma unroll
      for (int m = 0; m < 4; ++m)
#pragma unroll
        for (int n = 0; n < 4; ++n)
          acc[m][n] = __builtin_amdgcn_mfma_f32_16x16x32_bf16(
              af[m][ks], bv[n][ks], acc[m][n], 0, 0, 0);
  }

  float bvv[4];
#pragma unroll
  for (int n = 0; n < 4; ++n)
    bvv[n] = (kh == 0) ? bias[(size_t)e * ND + n0 + wc * 64 + n * 16 + (lane & 15)] : 0.f;
  ushort* dstp = EOout + kh * EOSLAB;
  int rq = (lane >> 4) << 2;
#pragma unroll
  for (int m = 0; m < 4; ++m) {
#pragma unroll
    for (int qq = 0; qq < 4; ++qq) {
      int rr = m0 + wr * 64 + m * 16 + rq + qq;
      if (rr < cnt) {
#pragma unroll
        for (int n = 0; n < 4; ++n) {
          int col = n0 + wc * 64 + n * 16 + (lane & 15);
          dstp[(size_t)(base + rr) * ND + col] = f2bf(acc[m][n][qq] + bvv[n]);
        }
      }
    }
  }
}

// ---------------- combine: out[t] = sum_k g_k * (EO0[pk] + EO1[pk]), eo bf16 ----------------
__global__ __launch_bounds__(256) void combine_kernel(
    const ushort* __restrict__ eo, const int* __restrict__ tok_ppos,
    const float* __restrict__ tok_gate, float* __restrict__ out)
{
  int t = blockIdx.x;
  int tid = threadIdx.x;
  int p0 = tok_ppos[t * 2], p1 = tok_ppos[t * 2 + 1];
  float g0 = tok_gate[t * 2], g1 = tok_gate[t * 2 + 1];
  ushort4 a0 = ((const ushort4*)(eo + (size_t)p0 * DDIM))[tid];
  ushort4 a1 = ((const ushort4*)(eo + EOSLAB + (size_t)p0 * DDIM))[tid];
  ushort4 b0 = ((const ushort4*)(eo + (size_t)p1 * DDIM))[tid];
  ushort4 b1 = ((const ushort4*)(eo + EOSLAB + (size_t)p1 * DDIM))[tid];
  float4 o;
  o.x = g0 * (bf2f(a0.x) + bf2f(a1.x)) + g1 * (bf2f(b0.x) + bf2f(b1.x));
  o.y = g0 * (bf2f(a0.y) + bf2f(a1.y)) + g1 * (bf2f(b0.y) + bf2f(b1.y));
  o.z = g0 * (bf2f(a0.z) + bf2f(a1.z)) + g1 * (bf2f(b0.z) + bf2f(b1.z));
  o.w = g0 * (bf2f(a0.w) + bf2f(a1.w)) + g1 * (bf2f(b0.w) + bf2f(b1.w));
  ((float4*)(out + (size_t)t * DDIM))[tid] = o;
}

extern "C" void kernel_launch(void* const* d_in, const int* in_sizes, int n_in,
                              void* d_out, int out_size, void* d_ws, size_t ws_size,
                              hipStream_t stream)
{
  const float* x     = (const float*)d_in[0];
  const float* noise = (const float*)d_in[1];
  const float* Wr    = (const float*)d_in[2];
  const float* br    = (const float*)d_in[3];
  const float* Wn    = (const float*)d_in[4];
  const float* bn    = (const float*)d_in[5];
  const float* W1    = (const float*)d_in[6];
  const float* b1    = (const float*)d_in[7];
  const float* W2    = (const float*)d_in[8];
  const float* b2    = (const float*)d_in[9];
  float* out = (float*)d_out;

  char* ws = (char*)d_ws;
  size_t o = 0;
  auto alloc = [&](size_t sz) {
    void* p = ws + o;
    o = (o + sz + 255) & ~(size_t)255;
    return p;
  };
  ushort* WT1 = (ushort*)alloc((size_t)NE * FDIM * DDIM * 2);       // 64 MB
  ushort* WT2 = (ushort*)alloc((size_t)NE * DDIM * FDIM * 2);       // 64 MB
  ushort* XB  = (ushort*)alloc((size_t)T_TOK * DDIM * 2);           // 8 MB
  ushort* H   = (ushort*)alloc((size_t)(NPAIR + 256) * FDIM * 2);   // 69 MB
  ushort* EO  = (ushort*)alloc(2 * EOSLAB * 2);                     // 35 MB
  int*    TOK_TOP  = (int*)alloc(T_TOK * 2 * 4);
  float*  TOK_GATE = (float*)alloc(T_TOK * 2 * 4);
  int*    TOK_PPOS = (int*)alloc(T_TOK * 2 * 4);
  int*    PAIR_TOK = (int*)alloc((NPAIR + 256) * 4);
  int*    OFF = (int*)alloc(64);
  int*    TILES128 = (int*)alloc((1 + MAXT128) * 4);
  int*    TILES256 = (int*)alloc((1 + MAXT256) * 4);

  router_w1t_kernel<<<1024 + 8192, 256, 0, stream>>>(x, noise, Wr, br, Wn, bn,
                                                     TOK_TOP, TOK_GATE, XB, W1, WT1);
  scan_scatter_kernel<<<1, 256, 0, stream>>>(TOK_TOP, OFF, TILES128, TILES256,
                                             PAIR_TOK, TOK_PPOS);
  // GEMM1: 256x256 8-phase, K=1024; surplus blocks transpose W2 -> WT2
  gemm8p_kernel<DDIM, FDIM, 1>
      <<<dim3(FDIM / 256, MAXT256), 512, 0, stream>>>(XB, WT1, OFF, TILES256, PAIR_TOK,
                                                      b1, H, W2, WT2);
  // GEMM2: 128x128 2-barrier (locked body), splitK=2 -> 1056 blocks; EO bf16 partials
  gemm4_kernel<FDIM, DDIM>
      <<<dim3(DDIM / 128 * 2, MAXT128), 256, 0, stream>>>(H, WT2, OFF, TILES128, b2, EO);
  combine_kernel<<<T_TOK, 256, 0, stream>>>(EO, TOK_PPOS, TOK_GATE, out);
}

// Round 22
// 289.779 us; speedup vs baseline: 1.0244x; 1.0244x over previous
//
#include <hip/hip_runtime.h>

#define T_TOK 4096
#define DDIM 1024
#define FDIM 4096
#define NE 8
#define NPAIR 8192
#define MAXT128 72
#define MAXT256 48

typedef short bf16x8 __attribute__((ext_vector_type(8)));
typedef float f32x4 __attribute__((ext_vector_type(4)));

__device__ inline unsigned short f2bf(float f) {
  union { float f; unsigned u; } a; a.f = f;
  unsigned r = a.u + 0x7fffu + ((a.u >> 16) & 1u);
  return (unsigned short)(r >> 16);
}

__device__ inline float bf2f(ushort u) {
  union { unsigned u; float f; } a; a.u = ((unsigned)u) << 16;
  return a.f;
}

__device__ __forceinline__ void gload16(const void* g, void* l) {
  __builtin_amdgcn_global_load_lds(
      (const __attribute__((address_space(1))) unsigned int*)g,
      (__attribute__((address_space(3))) unsigned int*)l, 16, 0, 0);
}

// ---------------- fused: router (blocks 0..1023) + W1 transpose (blocks 1024..9215) ----------------
__global__ __launch_bounds__(256) void router_w1t_kernel(
    const float* __restrict__ x, const float* __restrict__ noise,
    const float* __restrict__ Wr, const float* __restrict__ br,
    const float* __restrict__ Wn, const float* __restrict__ bn,
    int* __restrict__ tok_top, float* __restrict__ tok_gate,
    ushort* __restrict__ xb,
    const float* __restrict__ W1, ushort* __restrict__ WT1)
{
  if (blockIdx.x >= 1024) {
    __shared__ float tile[64][65];
    int idx = blockIdx.x - 1024;
    int z = idx >> 10;
    int rem = idx & 1023;
    int bx = rem & 63, by = rem >> 6;
    const float* src = W1 + (size_t)z * DDIM * FDIM;
    ushort* dst = WT1 + (size_t)z * FDIM * DDIM;
    int c0 = bx * 64, r0 = by * 64;
    int tid = threadIdx.x;
    int tr = tid >> 4;
    int tc4 = (tid & 15) * 4;
#pragma unroll
    for (int i = 0; i < 64; i += 16) {
      float4 v = *(const float4*)(src + (size_t)(r0 + tr + i) * FDIM + c0 + tc4);
      tile[tr + i][tc4] = v.x; tile[tr + i][tc4 + 1] = v.y;
      tile[tr + i][tc4 + 2] = v.z; tile[tr + i][tc4 + 3] = v.w;
    }
    __syncthreads();
    int rr = (tid & 7) * 8;
    int cbase = tid >> 3;
#pragma unroll
    for (int cc = 0; cc < 64; cc += 32) {
      int c = cbase + cc;
      ushort tmp[8];
#pragma unroll
      for (int j = 0; j < 8; ++j) tmp[j] = f2bf(tile[rr + j][c]);
      *(uint4*)(dst + (size_t)(c0 + c) * DDIM + r0 + rr) = *(uint4*)tmp;
    }
    return;
  }
  int t = blockIdx.x * 4 + (threadIdx.x >> 6);
  int lane = threadIdx.x & 63;
  const float* xr = x + (size_t)t * DDIM;
  ushort* xo = xb + (size_t)t * DDIM;
  float accR[NE] = {}, accN[NE] = {};
  for (int d = lane; d < DDIM; d += 64) {
    float xv = xr[d];
    xo[d] = f2bf(xv);
    const float* wr = Wr + (size_t)d * NE;
    const float* wn = Wn + (size_t)d * NE;
#pragma unroll
    for (int e = 0; e < NE; ++e) {
      accR[e] = fmaf(xv, wr[e], accR[e]);
      accN[e] = fmaf(xv, wn[e], accN[e]);
    }
  }
#pragma unroll
  for (int off = 32; off > 0; off >>= 1) {
#pragma unroll
    for (int e = 0; e < NE; ++e) {
      accR[e] += __shfl_xor(accR[e], off);
      accN[e] += __shfl_xor(accN[e], off);
    }
  }
  if (lane == 0) {
    float noisy[NE];
#pragma unroll
    for (int e = 0; e < NE; ++e) {
      float lg = accR[e] + br[e];
      float nl = accN[e] + bn[e];
      float sp = fmaxf(nl, 0.f) + log1pf(expf(-fabsf(nl)));
      noisy[e] = lg + noise[(size_t)t * NE + e] * sp;
    }
    int e0 = 0;
#pragma unroll
    for (int e = 1; e < NE; ++e) if (noisy[e] > noisy[e0]) e0 = e;
    int e1 = (e0 == 0) ? 1 : 0;
#pragma unroll
    for (int e = 0; e < NE; ++e)
      if (e != e0 && e != e1 && noisy[e] > noisy[e1]) e1 = e;
    float v0 = noisy[e0], v1 = noisy[e1];
    float ex = __expf(v1 - v0);
    float inv = 1.f / (1.f + ex);
    tok_top[t * 2] = e0; tok_top[t * 2 + 1] = e1;
    tok_gate[t * 2] = inv; tok_gate[t * 2 + 1] = ex * inv;
  }
}

// ---------------- deterministic count + PARALLEL scan + dual tile lists + scatter ----------------
__global__ __launch_bounds__(256) void scan_scatter_kernel(
    const int* __restrict__ tok_top, int* __restrict__ off,
    int* __restrict__ tiles128, int* __restrict__ tiles256,
    int* __restrict__ pair_tok, int* __restrict__ tok_ppos)
{
  __shared__ int smat[NE][256];
  __shared__ int tot[NE];
  __shared__ int loff[NE];
  int tid = threadIdx.x;
  int c[NE] = {};
  for (int i = 0; i < 16; ++i) {
    int t = tid * 16 + i;
    int e0 = tok_top[2 * t], e1 = tok_top[2 * t + 1];
#pragma unroll
    for (int e = 0; e < NE; ++e) c[e] += (e0 == e) + (e1 == e);
  }
#pragma unroll
  for (int e = 0; e < NE; ++e) smat[e][tid] = c[e];
  __syncthreads();
  {
    int ge = tid >> 5;
    int gl = tid & 31;
    int vals[8], s = 0;
#pragma unroll
    for (int j = 0; j < 8; ++j) { vals[j] = smat[ge][gl * 8 + j]; s += vals[j]; }
    int incl = s;
#pragma unroll
    for (int d = 1; d < 32; d <<= 1) {
      int o = __shfl_up(incl, d);
      if (gl >= d) incl += o;
    }
    int run = incl - s;
#pragma unroll
    for (int j = 0; j < 8; ++j) { smat[ge][gl * 8 + j] = run; run += vals[j]; }
    if (gl == 31) tot[ge] = incl;
  }
  __syncthreads();
  if (tid == 0) {
    int s = 0, nt1 = 0, nt2 = 0;
    for (int e = 0; e < NE; ++e) {
      loff[e] = s; off[e] = s;
      int t1 = (tot[e] + 127) >> 7;
      for (int m = 0; m < t1; ++m) tiles128[1 + nt1++] = (e << 8) | m;
      int t2 = (tot[e] + 255) >> 8;
      for (int m = 0; m < t2; ++m) tiles256[1 + nt2++] = (e << 8) | m;
      s += tot[e];
    }
    off[NE] = s;
    tiles128[0] = nt1;
    tiles256[0] = nt2;
  }
  __syncthreads();
  for (int i = 0; i < 16; ++i) {
    int t = tid * 16 + i;
#pragma unroll
    for (int k = 0; k < 2; ++k) {
      int e = tok_top[2 * t + k];
      int pos = loff[e] + smat[e][tid];
      smat[e][tid] = smat[e][tid] + 1;
      pair_tok[pos] = t;
      tok_ppos[2 * t + k] = pos;
    }
  }
}

// ---------------- 256x256 8-phase counted-vmcnt grouped GEMM1, 8 waves (2Mx4N) ----------------
// Surplus blocks: transpose W2 -> WT2 (two 64x64 tiles per iter) with cross-iteration
// register prefetch (2 tiles of loads in flight per thread -> ~2x memory parallelism).
template<int KD, int ND, int INDIR>
__global__ __launch_bounds__(512) void gemm8p_kernel(
    const ushort* __restrict__ A, const ushort* __restrict__ BT,
    const int* __restrict__ off, const int* __restrict__ tiles,
    const int* __restrict__ pair_tok, const float* __restrict__ bias,
    ushort* __restrict__ Hout,
    const float* __restrict__ W2src, ushort* __restrict__ WT2dst)
{
  constexpr int GX = ND / 256;
  constexpr int NKT = KD / 64;
  constexpr int NIT = NKT / 2;
  __shared__ __align__(16) char lds[2 * 65536];

  int total = tiles[0] * GX;
  int orig = blockIdx.x + GX * (int)blockIdx.y;
  if (orig >= total) {
    // ---- surplus: W2[e][F][D] -> WT2[e][D][F]; prefetched pipeline ----
    int S = GX * (int)gridDim.y - total;
    int half = threadIdx.x >> 8;
    int tid2 = threadIdx.x & 255;
    float (*tt)[65] = (float(*)[65])(lds + half * 16704);
    int tr = tid2 >> 4, tc4 = (tid2 & 15) * 4;
    int rr = (tid2 & 7) * 8, cbase = tid2 >> 3;
    int j0 = orig - total;
    float4 pvA, pvB, pvC, pvD;
    if (j0 < 4096) {
      int idx = 2 * j0 + half;
      int e2 = idx >> 10, rem = idx & 1023;
      int ft = rem >> 4, dt = rem & 15;
      const float* src = W2src + (size_t)e2 * FDIM * DDIM
                       + (size_t)(ft * 64 + tr) * DDIM + dt * 64 + tc4;
      pvA = *(const float4*)(src);
      pvB = *(const float4*)(src + (size_t)16 * DDIM);
      pvC = *(const float4*)(src + (size_t)32 * DDIM);
      pvD = *(const float4*)(src + (size_t)48 * DDIM);
    }
    for (int j = j0; j < 4096; j += S) {
      // write prefetched tile j into LDS
      tt[tr +  0][tc4] = pvA.x; tt[tr +  0][tc4 + 1] = pvA.y;
      tt[tr +  0][tc4 + 2] = pvA.z; tt[tr +  0][tc4 + 3] = pvA.w;
      tt[tr + 16][tc4] = pvB.x; tt[tr + 16][tc4 + 1] = pvB.y;
      tt[tr + 16][tc4 + 2] = pvB.z; tt[tr + 16][tc4 + 3] = pvB.w;
      tt[tr + 32][tc4] = pvC.x; tt[tr + 32][tc4 + 1] = pvC.y;
      tt[tr + 32][tc4 + 2] = pvC.z; tt[tr + 32][tc4 + 3] = pvC.w;
      tt[tr + 48][tc4] = pvD.x; tt[tr + 48][tc4 + 1] = pvD.y;
      tt[tr + 48][tc4 + 2] = pvD.z; tt[tr + 48][tc4 + 3] = pvD.w;
      int idx = 2 * j + half;
      int e2 = idx >> 10, rem = idx & 1023;
      int ft = rem >> 4, dt = rem & 15;
      ushort* dst = WT2dst + (size_t)e2 * DDIM * FDIM;
      int r0 = ft * 64, c0 = dt * 64;
      // issue prefetch for tile j+S (latency hides under store phase)
      int jn = j + S;
      if (jn < 4096) {
        int idxn = 2 * jn + half;
        int e2n = idxn >> 10, remn = idxn & 1023;
        int ftn = remn >> 4, dtn = remn & 15;
        const float* srcn = W2src + (size_t)e2n * FDIM * DDIM
                          + (size_t)(ftn * 64 + tr) * DDIM + dtn * 64 + tc4;
        pvA = *(const float4*)(srcn);
        pvB = *(const float4*)(srcn + (size_t)16 * DDIM);
        pvC = *(const float4*)(srcn + (size_t)32 * DDIM);
        pvD = *(const float4*)(srcn + (size_t)48 * DDIM);
      }
      __syncthreads();
#pragma unroll
      for (int cc = 0; cc < 64; cc += 32) {
        int c = cbase + cc;
        ushort tmp[8];
#pragma unroll
        for (int jj = 0; jj < 8; ++jj) tmp[jj] = f2bf(tt[rr + jj][c]);
        *(uint4*)(dst + (size_t)(c0 + c) * FDIM + r0 + rr) = *(uint4*)tmp;
      }
      __syncthreads();
    }
    return;
  }
  int q = total >> 3, r = total & 7, xcd = orig & 7, idx = orig >> 3;
  int wg = (xcd < r ? xcd * (q + 1) : r * (q + 1) + (xcd - r) * q) + idx;
  int ti = wg / GX, bx = wg - ti * GX;

  int te = tiles[1 + ti];
  int e = te >> 8, mt = te & 255;
  int base = off[e];
  int cnt = off[e + 1] - base;
  int m0 = mt << 8, n0 = bx << 8;

  int tid = threadIdx.x, lane = tid & 63, wid = tid >> 6;
  int wr = wid >> 2, wc = wid & 3;
  int lr = lane & 15, hi = lane >> 4;
  int swl = (lane & 7) << 4;
  int wrOff = wr * 16384;
  int wcLow = wc & 1;
  int wcHiOff = (wc >> 1) * 16384;

  const char* aptr[2][2];
  const char* bptr[2][2];
  {
    const char* Ab = (const char*)A;
    const char* Bb = (const char*)(BT + ((size_t)e * ND + n0) * KD);
#pragma unroll
    for (int h = 0; h < 2; ++h)
#pragma unroll
      for (int c = 0; c < 2; ++c) {
        int ch = c * 512 + tid;
        int rl = ch >> 3;
        int sc = ((ch & 7) * 16) ^ ((rl & 7) << 4);
        int mr = m0 + h * 128 + rl; if (mr >= cnt) mr = cnt - 1;
        int ar = INDIR ? pair_tok[base + mr] : base + mr;
        aptr[h][c] = Ab + (size_t)ar * (KD * 2) + sc;
        bptr[h][c] = Bb + (size_t)(h * 128 + rl) * (KD * 2) + sc;
      }
  }

#define SH_A(T, H)                                                        \
  if ((T) < NKT) {                                                        \
    char* d_ = lds + ((T) & 1) * 65536 + (H) * 16384 + tid * 16;          \
    gload16(aptr[H][0] + (T) * 128, d_);                                  \
    gload16(aptr[H][1] + (T) * 128, d_ + 8192);                           \
  }
#define SH_B(T, H)                                                        \
  if ((T) < NKT) {                                                        \
    char* d_ = lds + ((T) & 1) * 65536 + 32768 + (H) * 16384 + tid * 16;  \
    gload16(bptr[H][0] + (T) * 128, d_);                                  \
    gload16(bptr[H][1] + (T) * 128, d_ + 8192);                           \
  }
#define LDA(MH, BUF)                                                      \
  { _Pragma("unroll") for (int mm = 0; mm < 4; ++mm) {                    \
      int rr_ = (MH) * 64 + mm * 16 + lr;                                 \
      _Pragma("unroll") for (int ks = 0; ks < 2; ++ks)                    \
        af[mm][ks] = *(const bf16x8*)((BUF) + wrOff + rr_ * 128 +         \
                                      ((ks * 64 + hi * 16) ^ swl)); } }
#define LDB(NH, BUF, BV)                                                  \
  { _Pragma("unroll") for (int nn = 0; nn < 2; ++nn) {                    \
      int rr_ = wcLow * 64 + (NH) * 32 + nn * 16 + lr;                    \
      _Pragma("unroll") for (int ks = 0; ks < 2; ++ks)                    \
        BV[nn][ks] = *(const bf16x8*)((BUF) + 32768 + wcHiOff + rr_ * 128 + \
                                      ((ks * 64 + hi * 16) ^ swl)); } }
#define MMA(MH, NH, BV)                                                   \
  { _Pragma("unroll") for (int ks = 0; ks < 2; ++ks)                      \
    _Pragma("unroll") for (int mm = 0; mm < 4; ++mm)                      \
    _Pragma("unroll") for (int nn = 0; nn < 2; ++nn)                      \
      acc[(MH) * 4 + mm][(NH) * 2 + nn] =                                 \
        __builtin_amdgcn_mfma_f32_16x16x32_bf16(                          \
          af[mm][ks], BV[nn][ks], acc[(MH) * 4 + mm][(NH) * 2 + nn], 0, 0, 0); }
#define PH_MID                                                            \
  __builtin_amdgcn_sched_barrier(0);                                      \
  __builtin_amdgcn_s_barrier();                                           \
  asm volatile("s_waitcnt lgkmcnt(0)" ::: "memory");                      \
  __builtin_amdgcn_sched_barrier(0);                                      \
  __builtin_amdgcn_s_setprio(1);
#define PH_END                                                            \
  __builtin_amdgcn_s_setprio(0);                                          \
  __builtin_amdgcn_sched_barrier(0);                                      \
  __builtin_amdgcn_s_barrier();

  f32x4 acc[8][4] = {};
  bf16x8 af[4][2], bv0[2][2], bv1[2][2];

  SH_A(0, 0); SH_A(0, 1); SH_B(0, 0); SH_B(0, 1); SH_B(1, 0); SH_B(1, 1);
  asm volatile("s_waitcnt vmcnt(4)" ::: "memory");
  __builtin_amdgcn_sched_barrier(0);
  __builtin_amdgcn_s_barrier();

  const char* buf0 = lds;
  const char* buf1 = lds + 65536;

  for (int it = 0; it < NIT; ++it) {
    int t0 = 2 * it, t1 = t0 + 1;
    LDA(0, buf0); LDB(0, buf0, bv0);
    SH_A(t1, 0);
    PH_MID; MMA(0, 0, bv0); PH_END;
    LDB(1, buf0, bv1);
    SH_A(t1, 1);
    PH_MID; MMA(0, 1, bv1); PH_END;
    LDA(1, buf0);
    SH_B(t0 + 2, 0);
    PH_MID; MMA(1, 1, bv1); PH_END;
    SH_A(t0 + 2, 0);
    PH_MID; MMA(1, 0, bv0);
    __builtin_amdgcn_s_setprio(0);
    if (t0 + 2 < NKT) asm volatile("s_waitcnt vmcnt(4)" ::: "memory");
    else              asm volatile("s_waitcnt vmcnt(0)" ::: "memory");
    __builtin_amdgcn_sched_barrier(0);
    __builtin_amdgcn_s_barrier();
    LDA(0, buf1); LDB(0, buf1, bv0);
    SH_A(t0 + 2, 1);
    PH_MID; MMA(0, 0, bv0); PH_END;
    LDB(1, buf1, bv1);
    SH_B(t0 + 2, 1);
    PH_MID; MMA(0, 1, bv1); PH_END;
    LDA(1, buf1);
    SH_B(t1 + 2, 0);
    PH_MID; MMA(1, 1, bv1); PH_END;
    SH_B(t1 + 2, 1);
    PH_MID; MMA(1, 0, bv0);
    __builtin_amdgcn_s_setprio(0);
    if (t1 + 2 < NKT) asm volatile("s_waitcnt vmcnt(4)" ::: "memory");
    else              asm volatile("s_waitcnt vmcnt(0)" ::: "memory");
    __builtin_amdgcn_sched_barrier(0);
    __builtin_amdgcn_s_barrier();
  }

  int rq = hi << 2;
#pragma unroll
  for (int m = 0; m < 8; ++m) {
#pragma unroll
    for (int qq = 0; qq < 4; ++qq) {
      int rr2 = m0 + wr * 128 + m * 16 + rq + qq;
      if (rr2 < cnt) {
#pragma unroll
        for (int n = 0; n < 4; ++n) {
          int col = n0 + wc * 64 + n * 16 + lr;
          float v = fmaxf(acc[m][n][qq] + bias[(size_t)e * ND + col], 0.f);
          Hout[(size_t)(base + rr2) * ND + col] = f2bf(v);
        }
      }
    }
  }
#undef SH_A
#undef SH_B
#undef LDA
#undef LDB
#undef MMA
#undef PH_MID
#undef PH_END
}

// ---------------- GEMM2: 128x128, 4 waves, BK=64, 32KB single-buffer (locked R11 body) ----------------
// EPI==1 writes EO as bf16 (C + b2).
template<int KD, int ND, int EPI, int INDIR>
__global__ __launch_bounds__(256) void gemm4_kernel(
    const ushort* __restrict__ A, const ushort* __restrict__ BT,
    const int* __restrict__ off, const int* __restrict__ tiles,
    const int* __restrict__ pair_tok, const float* __restrict__ bias,
    ushort* __restrict__ Hout, ushort* __restrict__ EOout)
{
  constexpr int GX = ND / 128;
  constexpr int NKT = KD / 64;
  __shared__ __align__(16) ushort As[128 * 64];
  __shared__ __align__(16) ushort Bs[128 * 64];

  int total = tiles[0] * GX;
  int orig = blockIdx.x + GX * (int)blockIdx.y;
  if (orig >= total) return;
  int q = total >> 3, r = total & 7, xcd = orig & 7, idx = orig >> 3;
  int wg = (xcd < r ? xcd * (q + 1) : r * (q + 1) + (xcd - r) * q) + idx;
  int ti = wg / GX, bx = wg - ti * GX;

  int te = tiles[1 + ti];
  int e = te >> 8, mt = te & 255;
  int base = off[e];
  int cnt = off[e + 1] - base;
  int m0 = mt << 7, n0 = bx << 7;

  int tid = threadIdx.x, lane = tid & 63, wid = tid >> 6;
  int wr = wid >> 1, wc = wid & 1;

  int arow[4];
#pragma unroll
  for (int c = 0; c < 4; ++c) {
    int rl = (c * 256 + tid) >> 3;
    int mr = m0 + rl; if (mr >= cnt) mr = cnt - 1;
    arow[c] = INDIR ? pair_tok[base + mr] : base + mr;
  }
  const char* Ab = (const char*)A;
  const char* Bgb = (const char*)(BT + ((size_t)e * ND + n0) * KD);

  f32x4 acc[4][4] = {};

  for (int t = 0; t < NKT; ++t) {
    __syncthreads();
    int kb = t * 128;
#pragma unroll
    for (int c = 0; c < 4; ++c) {
      int ch = c * 256 + tid;
      int row = ch >> 3, b = (ch & 7) * 16;
      gload16(Ab + (size_t)arow[c] * (KD * 2) + kb + (b ^ ((row & 7) << 4)),
              (char*)As + ch * 16);
    }
#pragma unroll
    for (int c = 0; c < 4; ++c) {
      int ch = c * 256 + tid;
      int row = ch >> 3, b = (ch & 7) * 16;
      gload16(Bgb + (size_t)row * (KD * 2) + kb + (b ^ ((row & 7) << 4)),
              (char*)Bs + ch * 16);
    }
    __syncthreads();

    bf16x8 af[4][2], bv[4][2];
#pragma unroll
    for (int m = 0; m < 4; ++m) {
      int row = wr * 64 + m * 16 + (lane & 15);
      int sw = (row & 7) << 4;
#pragma unroll
      for (int ks = 0; ks < 2; ++ks)
        af[m][ks] = *(const bf16x8*)((const char*)As + row * 128 +
                                     ((ks * 64 + (lane >> 4) * 16) ^ sw));
    }
#pragma unroll
    for (int n = 0; n < 4; ++n) {
      int row = wc * 64 + n * 16 + (lane & 15);
      int sw = (row & 7) << 4;
#pragma unroll
      for (int ks = 0; ks < 2; ++ks)
        bv[n][ks] = *(const bf16x8*)((const char*)Bs + row * 128 +
                                     ((ks * 64 + (lane >> 4) * 16) ^ sw));
    }
#pragma unroll
    for (int ks = 0; ks < 2; ++ks)
#pragma unroll
      for (int m = 0; m < 4; ++m)
#pragma unroll
        for (int n = 0; n < 4; ++n)
          acc[m][n] = __builtin_amdgcn_mfma_f32_16x16x32_bf16(
              af[m][ks], bv[n][ks], acc[m][n], 0, 0, 0);
  }

  float bvv[4];
#pragma unroll
  for (int n = 0; n < 4; ++n)
    bvv[n] = bias[(size_t)e * ND + n0 + wc * 64 + n * 16 + (lane & 15)];
  int rq = (lane >> 4) << 2;
#pragma unroll
  for (int m = 0; m < 4; ++m) {
#pragma unroll
    for (int qq = 0; qq < 4; ++qq) {
      int rr = m0 + wr * 64 + m * 16 + rq + qq;
      if (rr < cnt) {
#pragma unroll
        for (int n = 0; n < 4; ++n) {
          int col = n0 + wc * 64 + n * 16 + (lane & 15);
          float v = acc[m][n][qq] + bvv[n];
          if (EPI == 0) v = fmaxf(v, 0.f);
          ushort* dstp = (EPI == 0) ? Hout : EOout;
          dstp[(size_t)(base + rr) * ND + col] = f2bf(v);
        }
      }
    }
  }
}

// ---------------- combine: out[t] = g0*eo[p0] + g1*eo[p1], eo in bf16 ----------------
__global__ __launch_bounds__(256) void combine_kernel(
    const ushort* __restrict__ eo, const int* __restrict__ tok_ppos,
    const float* __restrict__ tok_gate, float* __restrict__ out)
{
  int t = blockIdx.x;
  int tid = threadIdx.x;
  int p0 = tok_ppos[t * 2], p1 = tok_ppos[t * 2 + 1];
  float g0 = tok_gate[t * 2], g1 = tok_gate[t * 2 + 1];
  ushort4 a = ((const ushort4*)(eo + (size_t)p0 * DDIM))[tid];
  ushort4 b = ((const ushort4*)(eo + (size_t)p1 * DDIM))[tid];
  float4 o;
  o.x = g0 * bf2f(a.x) + g1 * bf2f(b.x);
  o.y = g0 * bf2f(a.y) + g1 * bf2f(b.y);
  o.z = g0 * bf2f(a.z) + g1 * bf2f(b.z);
  o.w = g0 * bf2f(a.w) + g1 * bf2f(b.w);
  ((float4*)(out + (size_t)t * DDIM))[tid] = o;
}

extern "C" void kernel_launch(void* const* d_in, const int* in_sizes, int n_in,
                              void* d_out, int out_size, void* d_ws, size_t ws_size,
                              hipStream_t stream)
{
  const float* x     = (const float*)d_in[0];
  const float* noise = (const float*)d_in[1];
  const float* Wr    = (const float*)d_in[2];
  const float* br    = (const float*)d_in[3];
  const float* Wn    = (const float*)d_in[4];
  const float* bn    = (const float*)d_in[5];
  const float* W1    = (const float*)d_in[6];
  const float* b1    = (const float*)d_in[7];
  const float* W2    = (const float*)d_in[8];
  const float* b2    = (const float*)d_in[9];
  float* out = (float*)d_out;

  char* ws = (char*)d_ws;
  size_t o = 0;
  auto alloc = [&](size_t sz) {
    void* p = ws + o;
    o = (o + sz + 255) & ~(size_t)255;
    return p;
  };
  ushort* WT1 = (ushort*)alloc((size_t)NE * FDIM * DDIM * 2);       // 64 MB
  ushort* WT2 = (ushort*)alloc((size_t)NE * DDIM * FDIM * 2);       // 64 MB
  ushort* XB  = (ushort*)alloc((size_t)T_TOK * DDIM * 2);           // 8 MB
  ushort* H   = (ushort*)alloc((size_t)(NPAIR + 256) * FDIM * 2);   // 69 MB
  ushort* EO  = (ushort*)alloc((size_t)(NPAIR + 256) * DDIM * 2);   // 17 MB
  int*    TOK_TOP  = (int*)alloc(T_TOK * 2 * 4);
  float*  TOK_GATE = (float*)alloc(T_TOK * 2 * 4);
  int*    TOK_PPOS = (int*)alloc(T_TOK * 2 * 4);
  int*    PAIR_TOK = (int*)alloc((NPAIR + 256) * 4);
  int*    OFF = (int*)alloc(64);
  int*    TILES128 = (int*)alloc((1 + MAXT128) * 4);
  int*    TILES256 = (int*)alloc((1 + MAXT256) * 4);

  router_w1t_kernel<<<1024 + 8192, 256, 0, stream>>>(x, noise, Wr, br, Wn, bn,
                                                     TOK_TOP, TOK_GATE, XB, W1, WT1);
  scan_scatter_kernel<<<1, 256, 0, stream>>>(TOK_TOP, OFF, TILES128, TILES256,
                                             PAIR_TOK, TOK_PPOS);
  // GEMM1: 256x256 8-phase, K=1024; surplus blocks transpose W2 -> WT2 (prefetched)
  gemm8p_kernel<DDIM, FDIM, 1>
      <<<dim3(FDIM / 256, MAXT256), 512, 0, stream>>>(XB, WT1, OFF, TILES256, PAIR_TOK,
                                                      b1, H, W2, WT2);
  // GEMM2: 128x128 2-barrier (locked), K=4096; EO = bf16(C + b2)
  gemm4_kernel<FDIM, DDIM, 1, 0>
      <<<dim3(DDIM / 128, MAXT128), 256, 0, stream>>>(H, WT2, OFF, TILES128, PAIR_TOK,
                                                      b2, nullptr, EO);
  combine_kernel<<<T_TOK, 256, 0, stream>>>(EO, TOK_PPOS, TOK_GATE, out);
}